// Round 16
// baseline (474.388 us; speedup 1.0000x reference)
//
#include <hip/hip_runtime.h>
#include <hip/hip_bf16.h>

// ---------------------------------------------------------------------------
// VQ-VAE forward, MFMA edition, round 16.
//   vs round 15 (440us): convt2 occupancy rebuild. Waves = 4 parity x 2 ocg,
//   acc[2][1] = 32 AGPR; Y-tile 2; phase regions 4k8 x 4rows x 34cols (544
//   slots, padded 640) + shared trash = 42KB LDS. __launch_bounds__(512,6)
//   caps regs at 85 -> 3 blocks/CU x 8 waves = 24 waves/CU (was 16).
//   ds:MFMA goes 1:1 (A-reads duplicated across g-waves) - LDS floor ~41us,
//   still under target. Counted-vmcnt + setprio kept. Rest = round 15.
// ---------------------------------------------------------------------------

typedef __attribute__((ext_vector_type(8)))  short  bf16x8;
typedef __attribute__((ext_vector_type(4)))  float  f32x4;
typedef __attribute__((ext_vector_type(16))) float  f32x16;

static constexpr int B_=32, C_=32, H_=64, W_=64, K_=1024;
static constexpr int NPOS = B_*H_*W_;      // 131072

__device__ __forceinline__ unsigned short f2bf(float f){
  unsigned u = __float_as_uint(f);
  u = u + 0x7FFFu + ((u>>16)&1u);        // round-to-nearest-even
  return (unsigned short)(u>>16);
}
__device__ __forceinline__ float bf2f(unsigned short h){
  return __uint_as_float(((unsigned)h)<<16);
}
__device__ __forceinline__ f32x16 mfma32(bf16x8 a, bf16x8 b, f32x16 c){
  return __builtin_amdgcn_mfma_f32_32x32x16_bf16(a,b,c,0,0,0);
}
__device__ __forceinline__ f32x4 mfma16(bf16x8 a, bf16x8 b, f32x4 c){
  return __builtin_amdgcn_mfma_f32_16x16x32_bf16(a,b,c,0,0,0);
}
// async global->LDS, 16B per lane; LDS dest = wave-uniform base + lane*16
__device__ __forceinline__ void gload16(const void* g, void* l){
  __builtin_amdgcn_global_load_lds(
      (const __attribute__((address_space(1))) void*)(unsigned long long)g,
      (__attribute__((address_space(3))) void*)(unsigned)(unsigned long long)l,
      16, 0, 0);
}
#define WAITVM(N) asm volatile("s_waitcnt vmcnt(" #N ")" ::: "memory")
__device__ __forceinline__ void barrier_raw(){
  asm volatile("" ::: "memory");
  __builtin_amdgcn_s_barrier();
  asm volatile("" ::: "memory");
}

// ---------------- prep: f64 codebook (row-major), e2, bf16x2 cb, weights ---
__global__ __launch_bounds__(256) void prep_kernel(
    const float* __restrict__ cb, const float* __restrict__ w1,
    const float* __restrict__ w2, const float* __restrict__ w3,
    double* __restrict__ cb64, double* __restrict__ e2,
    unsigned short* __restrict__ cbp_hi, unsigned short* __restrict__ cbp_lo,
    float* __restrict__ e2h,
    unsigned short* __restrict__ wt1p, unsigned short* __restrict__ wt2p,
    unsigned short* __restrict__ w3p, float* __restrict__ zpage,
    int* __restrict__ cnt) {
  int idx = blockIdx.x*256 + threadIdx.x;
  if (idx == 0) cnt[0] = 0;
  if (idx < 64) zpage[idx] = 0.f;
  if (idx < K_*C_) {
    float v = cb[idx];
    cb64[idx] = (double)v;
    unsigned short h = f2bf(v);
    cbp_hi[idx] = h;
    cbp_lo[idx] = f2bf(v - bf2f(h));
  }
  if (idx < K_) {
    double s = 0.0;
    #pragma unroll
    for (int c=0;c<C_;++c){ double v=(double)cb[idx*C_+c]; s+=v*v; }
    e2[idx] = s;
    e2h[idx] = -0.5f * (float)s;
  }
  if (idx < 65536) {  // wt1p  [p][c2][t4][g4][lane64][e8]
    int e=idx&7, lane=(idx>>3)&63, g=(idx>>9)&3, t=(idx>>11)&3, c=(idx>>13)&1, p=idx>>14;
    int ic = c*16 + (lane>>5)*8 + e;
    int oc = g*32 + (lane&31);
    int ky = 2*(t>>1) + (p>>1), kx = 2*(t&1) + (p&1);
    wt1p[idx] = f2bf(w1[((ic*128+oc)*4+ky)*4+kx]);
  }
  if (idx < 131072) { // wt2p  [p][m2][c4][t4][g2][lane64][e8]
    int e=idx&7, lane=(idx>>3)&63, g=(idx>>9)&1, t=(idx>>10)&3, c=(idx>>12)&3, m=(idx>>14)&1, p=idx>>15;
    int ic = m*64 + c*16 + (lane>>5)*8 + e;
    int oc = g*32 + (lane&31);
    int ky = 2*(t>>1) + (p>>1), kx = 2*(t&1) + (p&1);
    wt2p[idx] = f2bf(w2[((ic*64+oc)*4+ky)*4+kx]);
  }
  if (idx < 9216) {   // w3p  [t9][c2][lane64][e8]
    int e=idx&7, lane=(idx>>3)&63, c=(idx>>9)&1, t=idx>>10;
    int ic = c*32 + ((lane>>4)&3)*8 + e;
    int oc = lane&15;
    int dy = t/3, dx = t - 3*dy;
    w3p[idx] = (oc<3) ? f2bf(w3[((oc*64+ic)*3+dy)*3+dx]) : (unsigned short)0;
  }
}

// ---------------- z transpose + bf16x2 split: zt[n][c] --------------------
__global__ __launch_bounds__(256) void zprep_kernel(
    const float* __restrict__ z, unsigned short* __restrict__ zth,
    unsigned short* __restrict__ ztl) {
  int n = blockIdx.x*256 + threadIdx.x;     // 0..131071
  int b = n >> 12, hw = n & 4095;
  const float* zp = z + (((size_t)b*C_) << 12) + hw;
  unsigned short th[C_], tl[C_];
  #pragma unroll
  for (int c=0;c<C_;++c) {
    float v = zp[(size_t)c<<12];
    unsigned short h = f2bf(v);
    th[c] = h;
    tl[c] = f2bf(v - bf2f(h));
  }
  bf16x8* dh = (bf16x8*)(zth + (size_t)n*C_);
  bf16x8* dl = (bf16x8*)(ztl + (size_t)n*C_);
  #pragma unroll
  for (int v=0;v<4;++v){ dh[v]=((bf16x8*)th)[v]; dl[v]=((bf16x8*)tl)[v]; }
}

// ---------------- MFMA argmin screening ------------------------------------
__global__ __launch_bounds__(256) void quantm_kernel(
    const unsigned short* __restrict__ zth, const unsigned short* __restrict__ ztl,
    const unsigned short* __restrict__ cbp_hi, const unsigned short* __restrict__ cbp_lo,
    const float* __restrict__ e2h, const float* __restrict__ cb,
    unsigned short* __restrict__ q, int* __restrict__ cnt, int* __restrict__ list) {
  __shared__ bf16x8 ch[1024], cl[1024];     // 16KB + 16KB
  __shared__ float  el[256];
  int tid = threadIdx.x, lane = tid&63, wv = tid>>6;
  int m0 = blockIdx.x*128 + wv*32;
  int colL = lane&15, g = lane>>4;

  bf16x8 ah[2], al[2];
  #pragma unroll
  for (int mt=0;mt<2;++mt) {
    int pos = m0 + mt*16 + colL;
    ah[mt] = *(const bf16x8*)(zth + (size_t)pos*C_ + g*8);
    al[mt] = *(const bf16x8*)(ztl + (size_t)pos*C_ + g*8);
  }

  float b1[2][4], b2[2][4]; int i1[2][4];
  #pragma unroll
  for (int mt=0;mt<2;++mt)
    #pragma unroll
    for (int r=0;r<4;++r){ b1[mt][r]=-3e38f; b2[mt][r]=-3e38f; i1[mt][r]=0; }

  for (int cb0 = 0; cb0 < K_; cb0 += 256) {
    __syncthreads();
    {
      const bf16x8* sh = (const bf16x8*)cbp_hi + cb0*4;
      const bf16x8* sl = (const bf16x8*)cbp_lo + cb0*4;
      #pragma unroll
      for (int v=0;v<4;++v){ ch[tid + v*256] = sh[tid + v*256];
                             cl[tid + v*256] = sl[tid + v*256]; }
      el[tid] = e2h[cb0 + tid];
    }
    __syncthreads();
    #pragma unroll
    for (int nt=0; nt<16; ++nt) {
      int cloc = nt*16 + colL;
      float ei = el[cloc];
      bf16x8 bh = ch[cloc*4 + g];
      bf16x8 bl = cl[cloc*4 + g];
      int nidx = cb0 + cloc;
      #pragma unroll
      for (int mt=0;mt<2;++mt) {
        f32x4 acc = {ei, ei, ei, ei};
        acc = mfma16(al[mt], bh, acc);
        acc = mfma16(ah[mt], bl, acc);
        acc = mfma16(ah[mt], bh, acc);
        #pragma unroll
        for (int r=0;r<4;++r) {
          float s = acc[r];
          b2[mt][r] = fmaxf(b2[mt][r], fminf(s, b1[mt][r]));
          if (s > b1[mt][r]) { b1[mt][r] = s; i1[mt][r] = nidx; }
        }
      }
    }
  }

  #pragma unroll
  for (int mask=1; mask<16; mask<<=1) {
    #pragma unroll
    for (int mt=0;mt<2;++mt)
      #pragma unroll
      for (int r=0;r<4;++r) {
        float o1 = __shfl_xor(b1[mt][r], mask);
        float o2 = __shfl_xor(b2[mt][r], mask);
        int   oi = __shfl_xor(i1[mt][r], mask);
        float nb2 = fmaxf(fminf(b1[mt][r], o1), fmaxf(b2[mt][r], o2));
        if (o1 > b1[mt][r]) { b1[mt][r] = o1; i1[mt][r] = oi; }
        b2[mt][r] = nb2;
      }
  }

  #pragma unroll
  for (int mt=0;mt<2;++mt)
    #pragma unroll
    for (int r=0;r<4;++r) {
      int m = m0 + mt*16 + g*4 + r;
      int idx = i1[mt][r];
      unsigned h0 = f2bf(cb[idx*C_ + 2*colL]);
      unsigned h1 = f2bf(cb[idx*C_ + 2*colL + 1]);
      ((unsigned*)q)[(((size_t)(colL>>2))*NPOS + m)*4 + (colL&3)] = h0 | (h1<<16);
      if (colL == 0 && (b1[mt][r] - b2[mt][r]) < 0.02f) {
        int slot = atomicAdd(cnt, 1);
        list[slot] = m;
      }
    }
}

// ---------------- exact f64 refine, LDS-staged codebook --------------------
__global__ __launch_bounds__(256) void refine_kernel(
    const int* __restrict__ cnt, const int* __restrict__ list,
    const float* __restrict__ z, const double* __restrict__ cb64,
    const double* __restrict__ e2, const float* __restrict__ cb,
    unsigned short* __restrict__ q) {
  __shared__ double lcb[64*33];             // 16.9KB
  __shared__ double le2[64];
  int tid = threadIdx.x, lane = tid&63, wv = tid>>6;
  int n_ref = cnt[0];
  int stride = (int)gridDim.x * 4;
  for (int base = 0; base < n_ref; base += stride) {
    int widx = base + (int)blockIdx.x*4 + wv;
    bool active = widx < n_ref;
    int m = active ? list[widx] : 0;
    double zr[C_];
    if (active) {
      int b = m >> 12, hw = m & 4095;
      const float* zp = z + (((size_t)b*C_) << 12) + hw;
      #pragma unroll
      for (int c=0;c<C_;++c) zr[c] = (double)zp[(size_t)c<<12];
    }
    double best = -1e300; int bi = 0;
    for (int ck = 0; ck < 16; ++ck) {
      __syncthreads();
      {
        const double* src = cb64 + (size_t)ck*2048 + (size_t)tid*8;
        int row = tid >> 2, col = (tid & 3)*8;
        #pragma unroll
        for (int j=0;j<8;++j) lcb[row*33 + col + j] = src[j];
        if (tid < 64) le2[tid] = e2[ck*64 + tid];
      }
      __syncthreads();
      if (active) {
        const double* e = &lcb[lane*33];
        double a0=0,a1=0,a2=0,a3=0;
        #pragma unroll
        for (int c=0;c<C_;c+=4) {
          a0 += zr[c  ]*e[c  ]; a1 += zr[c+1]*e[c+1];
          a2 += zr[c+2]*e[c+2]; a3 += zr[c+3]*e[c+3];
        }
        double s = 2.0*((a0+a1)+(a2+a3)) - le2[lane];
        if (s > best) { best = s; bi = ck*64 + lane; }
      }
    }
    #pragma unroll
    for (int mask=1; mask<64; mask<<=1) {
      double ob = __shfl_xor(best, mask);
      int    oi = __shfl_xor(bi, mask);
      if (ob > best || (ob == best && oi < bi)) { best = ob; bi = oi; }
    }
    if (active && lane < 16) {
      unsigned h0 = f2bf(cb[bi*C_ + 2*lane]);
      unsigned h1 = f2bf(cb[bi*C_ + 2*lane + 1]);
      ((unsigned*)q)[(((size_t)(lane>>2))*NPOS + m)*4 + (lane&3)] = h0 | (h1<<16);
    }
  }
}

// ---------------- convT1: 32->128, parity implicit GEMM --------------------
// in: q [cg4][n][8]; out: x1 [bl][cg16][128][128][8]
__global__ __launch_bounds__(256) void convt1_kernel(
    const unsigned short* __restrict__ q, const unsigned short* __restrict__ wt1p,
    const float* __restrict__ b1, const float* __restrict__ zpage,
    unsigned short* __restrict__ x1, int b0) {
  __shared__ unsigned short At[4*4*34*8];   // [k8][r][c][8] 8.5KB
  int tid = threadIdx.x;
  int p = tid>>6, py=(tid>>7)&1, px=(tid>>6)&1;
  int lane = tid&63, xi = lane&31, half = lane>>5, ocl = lane&31;
  int bl = blockIdx.z, b = b0 + bl;
  int Y0 = blockIdx.y*2, X0 = blockIdx.x*32;

  for (int s = tid; s < 544; s += 256) {
    int t = (s*1928)>>16;                   // s/34
    int c = s - t*34;
    int r = t & 3, k8 = t >> 2;
    int hg = Y0-1+r, wg = X0-1+c;
    const unsigned short* src =
        (hg>=0 && hg<64 && wg>=0 && wg<64)
            ? q + ((size_t)k8*NPOS + ((b<<12) + hg*64 + wg))*8
            : (const unsigned short*)zpage;
    *(bf16x8*)&At[s*8] = *(const bf16x8*)src;
  }
  __syncthreads();

  f32x16 acc[2][4];
  #pragma unroll
  for (int g=0;g<4;++g){
    float bv = b1[g*32+ocl];
    #pragma unroll
    for (int yr=0;yr<2;++yr){
      #pragma unroll
      for (int r=0;r<16;++r) acc[yr][g][r]=bv;
    }
  }

  #pragma unroll
  for (int c16=0;c16<2;++c16) {
    #pragma unroll
    for (int t=0;t<4;++t) {
      int j=t>>1, kx=t&1;
      int col = xi+px+kx;
      int rb = (c16*2+half)*4 + py + j;
      bf16x8 a0 = *(const bf16x8*)&At[((rb+0)*34+col)*8];
      bf16x8 a1 = *(const bf16x8*)&At[((rb+1)*34+col)*8];
      const unsigned short* wb = wt1p + ((size_t)(((p*2+c16)*4+t)*4)*64 + lane)*8;
      #pragma unroll
      for (int g=0;g<4;++g) {
        bf16x8 bf = *(const bf16x8*)(wb + g*512);
        acc[0][g] = mfma32(a0, bf, acc[0][g]);
        acc[1][g] = mfma32(a1, bf, acc[1][g]);
      }
    }
  }

  #pragma unroll
  for (int yr=0;yr<2;++yr) {
    int Y = 2*(Y0+yr)+py;
    #pragma unroll
    for (int g=0;g<4;++g) {
      int oc = g*32 + ocl, cg = oc>>3, o8 = oc&7;
      unsigned short* dst = x1 + ((((size_t)bl*16 + cg)*128 + Y)*128 + (2*X0+px))*8 + o8;
      #pragma unroll
      for (int r=0;r<16;++r) {
        int xo = (r&3) + 8*(r>>2) + 4*half;
        dst[(size_t)xo*16] = f2bf(fmaxf(acc[yr][g][r], 0.f));
      }
    }
  }
}

// ---------------- convT2: 128->64, occupancy build ------------------------
// waves = 4 parity x 2 ocg; acc[2 yr] (32 AGPR); Y-tile 2; phase regions
// 4k8 x 4row x 34col = 544 slots (pad 640) + 64-slot trash = 42KB LDS.
// __launch_bounds__(512,6): <=85 regs -> 3 blocks/CU = 24 waves/CU.
__global__ __launch_bounds__(512, 6) void convt2_kernel(
    const unsigned short* __restrict__ x1, const unsigned short* __restrict__ wt2p,
    const float* __restrict__ b2, const float* __restrict__ zpage,
    unsigned short* __restrict__ x2) {
  __shared__ unsigned short At[(4*640 + 64)*8];  // 41.98KB
  int tid = threadIdx.x;
  int wv = __builtin_amdgcn_readfirstlane(tid>>6);
  int lane = tid&63;
  int p = wv>>1, g = wv&1;
  int py = p>>1, px = p&1;
  int xi = lane&31, half = lane>>5, ocl = lane&31;
  int bl = blockIdx.z;
  int Y0 = blockIdx.y*2, X0 = blockIdx.x*32;

  auto issue = [&](int P) {
    int m = P>>1, h = P&1;
    const unsigned short* xsrc = x1 + ((size_t)bl*16 + m*8 + h*4)*128*128*8;
    #pragma unroll
    for (int it = 0; it < 2; ++it) {
      int sbase = it*512 + wv*64;           // wave-uniform
      bool realdst = (sbase < 576);         // wv0/it1 covers 512..575
      int s = sbase + lane;
      int k8l = (s*482)>>16;                // s/136
      int rem = s - k8l*136;
      int r = (rem*1928)>>16;               // rem/34
      int c = rem - r*34;
      int hg = Y0-1+r, wg = X0-1+c;
      bool v = (s < 544) && hg>=0 && hg<128 && wg>=0 && wg<128;
      const void* src = v ? (const void*)(xsrc + (((size_t)k8l*128 + hg)*128 + wg)*8)
                          : (const void*)zpage;
      void* dst = realdst ? (void*)&At[((size_t)P*640 + sbase)*8]
                          : (void*)&At[(size_t)2560*8];  // shared trash
      gload16(src, dst);
    }
  };

  f32x16 acc[2];
  {
    float bv = b2[g*32+ocl];
    #pragma unroll
    for (int yr=0;yr<2;++yr)
      #pragma unroll
      for (int r=0;r<16;++r) acc[yr][r]=bv;
  }

  auto compute = [&](int P) {
    int m = P>>1;
    const unsigned short* Ab = &At[(size_t)P*640*8];
    __builtin_amdgcn_s_setprio(1);
    #pragma unroll
    for (int ci=0; ci<2; ++ci) {
      int c16 = (P&1)*2 + ci;
      int k8l = 2*ci + half;
      #pragma unroll
      for (int t=0;t<4;++t) {
        int j=t>>1, kx=t&1;
        int col = xi+px+kx;
        int base = (k8l*4 + py + j)*34 + col;
        bf16x8 a0 = *(const bf16x8*)&Ab[(base     )*8];
        bf16x8 a1 = *(const bf16x8*)&Ab[(base + 34)*8];
        const unsigned short* wb = wt2p +
            ((size_t)(((((p*2+m)*4+c16)*4+t)*2) + g)*64 + lane)*8;
        bf16x8 bf = *(const bf16x8*)wb;
        acc[0] = mfma32(a0, bf, acc[0]);
        acc[1] = mfma32(a1, bf, acc[1]);
      }
    }
    __builtin_amdgcn_s_setprio(0);
  };

  issue(0); issue(1); issue(2);   // 6 outstanding per wave
  WAITVM(4); barrier_raw();       // phase 0 resident
  compute(0);
  issue(3);                       // staging for ph1,2,3 in flight
  WAITVM(4); barrier_raw();       // phase 1 resident
  compute(1);
  WAITVM(2); barrier_raw();       // phase 2 resident
  compute(2);
  WAITVM(0); barrier_raw();       // phase 3 resident
  compute(3);

  #pragma unroll
  for (int yr=0;yr<2;++yr) {
    int Y = 2*(Y0 + yr) + py;
    int oc = g*32 + ocl, cg = oc>>3, o8 = oc&7;
    unsigned short* dst = x2 + ((((size_t)bl*8 + cg)*256 + Y)*256 + (2*X0+px))*8 + o8;
    #pragma unroll
    for (int r=0;r<16;++r) {
      int xo = (r&3) + 8*(r>>2) + 4*half;
      dst[(size_t)xo*16] = f2bf(fmaxf(acc[yr][r], 0.f));
    }
  }
}

// ---------------- conv3 3x3 64->3(+13 pad) + sigmoid, MFMA 16x16x32 --------
// in: x2 [bl][cg8][256][256][8]. 32-col x 8-row tile, 512 threads,
// double-buffered async staging (round-15 version).
__global__ __launch_bounds__(512) void conv3_kernel(
    const unsigned short* __restrict__ x2, const unsigned short* __restrict__ w3p,
    const float* __restrict__ b3, const float* __restrict__ zpage,
    float* __restrict__ out, int b0) {
  __shared__ unsigned short Xt[2][1536*8];  // 48KB, [k8 4][row 10][col 34][8]
  int tid = threadIdx.x, w = tid>>6, lane = tid&63;
  int xi = lane&15, k8A = (lane>>4)&3, oc = lane&15;
  int bl = blockIdx.z, b = b0 + bl;
  int y0 = blockIdx.y*8, x0 = blockIdx.x*32;
  int y = y0 + w;

  auto stage = [&](int c, int buf) {
    #pragma unroll
    for (int i=0;i<3;++i) {
      int sbase = i*512 + w*64;             // wave-uniform
      int s = sbase + lane;
      int t = (s*1928)>>16;                 // s/34
      int cc = s - t*34;
      int k8 = (t*26)>>8;                   // t/10
      int r = t - k8*10;
      int rf = y0-1+r, cf = x0-1+cc;
      bool ok = (s < 1360) && rf>=0 && rf<256 && cf>=0 && cf<256;
      const void* src = ok
          ? (const void*)(x2 + ((((size_t)bl*8 + c*4 + k8)*256 + rf)*256 + cf)*8)
          : (const void*)zpage;
      gload16(src, (void*)&Xt[buf][sbase*8]);
    }
  };

  f32x4 acc[2];
  float bv = (oc<3) ? b3[oc] : 0.f;
  acc[0][0]=bv; acc[0][1]=bv; acc[0][2]=bv; acc[0][3]=bv;
  acc[1][0]=bv; acc[1][1]=bv; acc[1][2]=bv; acc[1][3]=bv;

  auto compute = [&](int c, int buf) {
    #pragma unroll
    for (int t=0;t<9;++t) {
      int dy = t/3, dx = t - 3*dy;
      bf16x8 bf = *(const bf16x8*)(w3p + ((size_t)(t*2+c)*64 + lane)*8);
      #pragma unroll
      for (int mt=0;mt<2;++mt) {
        bf16x8 a = *(const bf16x8*)&Xt[buf][((size_t)(k8A*10 + (w+dy))*34 + (mt*16 + xi + dx))*8];
        acc[mt] = mfma16(a, bf, acc[mt]);
      }
    }
  };

  stage(0, 0);
  WAITVM(0); barrier_raw();     // buf0 resident
  stage(1, 1);                  // async, overlaps compute(c0)
  compute(0, 0);
  WAITVM(0); barrier_raw();     // buf1 resident
  compute(1, 1);

  if (oc < 3) {
    #pragma unroll
    for (int mt=0;mt<2;++mt) {
      f32x4 v;
      #pragma unroll
      for (int r=0;r<4;++r) v[r] = 1.f/(1.f + __expf(-acc[mt][r]));
      int x = x0 + mt*16 + ((lane>>4)&3)*4;
      *(f32x4*)(out + (((size_t)b*3 + oc)*256 + y)*256 + x) = v;
    }
  }
}

// ---------------------------------------------------------------------------
extern "C" void kernel_launch(void* const* d_in, const int* in_sizes, int n_in,
                              void* d_out, int out_size, void* d_ws, size_t ws_size,
                              hipStream_t stream) {
  const float* z  = (const float*)d_in[0];
  const float* cb = (const float*)d_in[1];
  const float* w1 = (const float*)d_in[2];
  const float* b1 = (const float*)d_in[3];
  const float* w2 = (const float*)d_in[4];
  const float* b2 = (const float*)d_in[5];
  const float* w3 = (const float*)d_in[6];
  const float* b3 = (const float*)d_in[7];
  float* out = (float*)d_out;

  char* ws = (char*)d_ws;
  size_t off = 0;
  auto alloc = [&](size_t bytes) -> void* {
    void* p = (void*)(ws + off);
    off += (bytes + 255) & ~(size_t)255;
    return p;
  };
  double* cb64         = (double*)alloc((size_t)K_*C_*8);
  double* e2           = (double*)alloc((size_t)K_*8);
  float*  zpage        = (float*)alloc(256);
  unsigned short* cbph = (unsigned short*)alloc((size_t)K_*C_*2);
  unsigned short* cbpl = (unsigned short*)alloc((size_t)K_*C_*2);
  float*  e2h          = (float*)alloc((size_t)K_*4);
  int*    cnt          = (int*)alloc(256);
  int*    list         = (int*)alloc((size_t)NPOS*4);
  unsigned short* zth  = (unsigned short*)alloc((size_t)NPOS*C_*2);
  unsigned short* ztl  = (unsigned short*)alloc((size_t)NPOS*C_*2);
  unsigned short* wt1p = (unsigned short*)alloc((size_t)65536*2);
  unsigned short* wt2p = (unsigned short*)alloc((size_t)131072*2);
  unsigned short* w3p  = (unsigned short*)alloc((size_t)9216*2);
  unsigned short* q    = (unsigned short*)alloc((size_t)NPOS*C_*2);
  size_t fixed = off;

  // per-batch: x1 16*128*128*8 bf16 (4.19MB) + x2 8*256*256*8 bf16 (8.39MB)
  size_t per_b = ((size_t)16*128*128*8 + (size_t)8*256*256*8) * 2;
  long long avail = (long long)ws_size - (long long)fixed;
  int chunk = (avail >= (long long)per_b) ? (int)(avail / (long long)per_b) : 1;
  if (chunk > B_) chunk = B_;
  // clamp to a divisor of 32 (avoid a lopsided tail dispatch)
  if      (chunk >= 32) chunk = 32;
  else if (chunk >= 16) chunk = 16;
  else if (chunk >=  8) chunk =  8;
  else if (chunk >=  4) chunk =  4;
  else if (chunk >=  2) chunk =  2;
  else                  chunk =  1;
  unsigned short* x1 = (unsigned short*)alloc((size_t)chunk*16*128*128*8*2);
  unsigned short* x2 = (unsigned short*)alloc((size_t)chunk*8*256*256*8*2);

  prep_kernel<<<512, 256, 0, stream>>>(cb, w1, w2, w3, cb64, e2, cbph, cbpl,
                                       e2h, wt1p, wt2p, w3p, zpage, cnt);
  zprep_kernel<<<512, 256, 0, stream>>>(z, zth, ztl);
  quantm_kernel<<<1024, 256, 0, stream>>>(zth, ztl, cbph, cbpl, e2h, cb,
                                          q, cnt, list);
  refine_kernel<<<512, 256, 0, stream>>>(cnt, list, z, cb64, e2, cb, q);

  for (int b0 = 0; b0 < B_; b0 += chunk) {
    int nb = (B_ - b0 < chunk) ? (B_ - b0) : chunk;
    convt1_kernel<<<dim3(2,32,nb), 256, 0, stream>>>(q, wt1p, b1, zpage, x1, b0);
    convt2_kernel<<<dim3(4,64,nb), 512, 0, stream>>>(x1, wt2p, b2, zpage, x2);
    conv3_kernel <<<dim3(8,32,nb), 512, 0, stream>>>(x2, w3p, b3, zpage, out, b0);
  }
}

// Round 17
// 435.793 us; speedup vs baseline: 1.0886x; 1.0886x over previous
//
#include <hip/hip_runtime.h>
#include <hip/hip_bf16.h>

// ---------------------------------------------------------------------------
// VQ-VAE forward, MFMA edition, round 17 = round 14 restored (best: 438us).
//   quant: bf16x2-split MFMA screening + LDS-staged f64 refine.
//   convt1: parity implicit GEMM (32->128).
//   convt2: 4-phase counted-vmcnt pipeline + s_setprio (T5), 8 waves.
//   conv3: y-tile 8 @ 512 threads, 42KB LDS, halo 1.25.
//   chunk = ws-derived, clamped to a divisor of 32 (equal splits).
// Round-16's occupancy rebuild (Y2/g-split) regressed: halo fetch +30%,
// LDS reads x2 beat the occupancy win. This config is the measured optimum
// across 7 convt2 schedule variants.
// ---------------------------------------------------------------------------

typedef __attribute__((ext_vector_type(8)))  short  bf16x8;
typedef __attribute__((ext_vector_type(4)))  float  f32x4;
typedef __attribute__((ext_vector_type(16))) float  f32x16;

static constexpr int B_=32, C_=32, H_=64, W_=64, K_=1024;
static constexpr int NPOS = B_*H_*W_;      // 131072

__device__ __forceinline__ unsigned short f2bf(float f){
  unsigned u = __float_as_uint(f);
  u = u + 0x7FFFu + ((u>>16)&1u);        // round-to-nearest-even
  return (unsigned short)(u>>16);
}
__device__ __forceinline__ float bf2f(unsigned short h){
  return __uint_as_float(((unsigned)h)<<16);
}
__device__ __forceinline__ f32x16 mfma32(bf16x8 a, bf16x8 b, f32x16 c){
  return __builtin_amdgcn_mfma_f32_32x32x16_bf16(a,b,c,0,0,0);
}
__device__ __forceinline__ f32x4 mfma16(bf16x8 a, bf16x8 b, f32x4 c){
  return __builtin_amdgcn_mfma_f32_16x16x32_bf16(a,b,c,0,0,0);
}
// async global->LDS, 16B per lane; LDS dest = wave-uniform base + lane*16
__device__ __forceinline__ void gload16(const void* g, void* l){
  __builtin_amdgcn_global_load_lds(
      (const __attribute__((address_space(1))) void*)(unsigned long long)g,
      (__attribute__((address_space(3))) void*)(unsigned)(unsigned long long)l,
      16, 0, 0);
}
#define WAITVM(N) asm volatile("s_waitcnt vmcnt(" #N ")" ::: "memory")
__device__ __forceinline__ void barrier_raw(){
  asm volatile("" ::: "memory");
  __builtin_amdgcn_s_barrier();
  asm volatile("" ::: "memory");
}

// ---------------- prep: f64 codebook (row-major), e2, bf16x2 cb, weights ---
__global__ __launch_bounds__(256) void prep_kernel(
    const float* __restrict__ cb, const float* __restrict__ w1,
    const float* __restrict__ w2, const float* __restrict__ w3,
    double* __restrict__ cb64, double* __restrict__ e2,
    unsigned short* __restrict__ cbp_hi, unsigned short* __restrict__ cbp_lo,
    float* __restrict__ e2h,
    unsigned short* __restrict__ wt1p, unsigned short* __restrict__ wt2p,
    unsigned short* __restrict__ w3p, float* __restrict__ zpage,
    int* __restrict__ cnt) {
  int idx = blockIdx.x*256 + threadIdx.x;
  if (idx == 0) cnt[0] = 0;
  if (idx < 64) zpage[idx] = 0.f;
  if (idx < K_*C_) {
    float v = cb[idx];
    cb64[idx] = (double)v;
    unsigned short h = f2bf(v);
    cbp_hi[idx] = h;
    cbp_lo[idx] = f2bf(v - bf2f(h));
  }
  if (idx < K_) {
    double s = 0.0;
    #pragma unroll
    for (int c=0;c<C_;++c){ double v=(double)cb[idx*C_+c]; s+=v*v; }
    e2[idx] = s;
    e2h[idx] = -0.5f * (float)s;
  }
  if (idx < 65536) {  // wt1p  [p][c2][t4][g4][lane64][e8]
    int e=idx&7, lane=(idx>>3)&63, g=(idx>>9)&3, t=(idx>>11)&3, c=(idx>>13)&1, p=idx>>14;
    int ic = c*16 + (lane>>5)*8 + e;
    int oc = g*32 + (lane&31);
    int ky = 2*(t>>1) + (p>>1), kx = 2*(t&1) + (p&1);
    wt1p[idx] = f2bf(w1[((ic*128+oc)*4+ky)*4+kx]);
  }
  if (idx < 131072) { // wt2p  [p][m2][c4][t4][g2][lane64][e8]
    int e=idx&7, lane=(idx>>3)&63, g=(idx>>9)&1, t=(idx>>10)&3, c=(idx>>12)&3, m=(idx>>14)&1, p=idx>>15;
    int ic = m*64 + c*16 + (lane>>5)*8 + e;
    int oc = g*32 + (lane&31);
    int ky = 2*(t>>1) + (p>>1), kx = 2*(t&1) + (p&1);
    wt2p[idx] = f2bf(w2[((ic*64+oc)*4+ky)*4+kx]);
  }
  if (idx < 9216) {   // w3p  [t9][c2][lane64][e8]
    int e=idx&7, lane=(idx>>3)&63, c=(idx>>9)&1, t=idx>>10;
    int ic = c*32 + ((lane>>4)&3)*8 + e;
    int oc = lane&15;
    int dy = t/3, dx = t - 3*dy;
    w3p[idx] = (oc<3) ? f2bf(w3[((oc*64+ic)*3+dy)*3+dx]) : (unsigned short)0;
  }
}

// ---------------- z transpose + bf16x2 split: zt[n][c] --------------------
__global__ __launch_bounds__(256) void zprep_kernel(
    const float* __restrict__ z, unsigned short* __restrict__ zth,
    unsigned short* __restrict__ ztl) {
  int n = blockIdx.x*256 + threadIdx.x;     // 0..131071
  int b = n >> 12, hw = n & 4095;
  const float* zp = z + (((size_t)b*C_) << 12) + hw;
  unsigned short th[C_], tl[C_];
  #pragma unroll
  for (int c=0;c<C_;++c) {
    float v = zp[(size_t)c<<12];
    unsigned short h = f2bf(v);
    th[c] = h;
    tl[c] = f2bf(v - bf2f(h));
  }
  bf16x8* dh = (bf16x8*)(zth + (size_t)n*C_);
  bf16x8* dl = (bf16x8*)(ztl + (size_t)n*C_);
  #pragma unroll
  for (int v=0;v<4;++v){ dh[v]=((bf16x8*)th)[v]; dl[v]=((bf16x8*)tl)[v]; }
}

// ---------------- MFMA argmin screening ------------------------------------
__global__ __launch_bounds__(256) void quantm_kernel(
    const unsigned short* __restrict__ zth, const unsigned short* __restrict__ ztl,
    const unsigned short* __restrict__ cbp_hi, const unsigned short* __restrict__ cbp_lo,
    const float* __restrict__ e2h, const float* __restrict__ cb,
    unsigned short* __restrict__ q, int* __restrict__ cnt, int* __restrict__ list) {
  __shared__ bf16x8 ch[1024], cl[1024];     // 16KB + 16KB
  __shared__ float  el[256];
  int tid = threadIdx.x, lane = tid&63, wv = tid>>6;
  int m0 = blockIdx.x*128 + wv*32;
  int colL = lane&15, g = lane>>4;

  bf16x8 ah[2], al[2];
  #pragma unroll
  for (int mt=0;mt<2;++mt) {
    int pos = m0 + mt*16 + colL;
    ah[mt] = *(const bf16x8*)(zth + (size_t)pos*C_ + g*8);
    al[mt] = *(const bf16x8*)(ztl + (size_t)pos*C_ + g*8);
  }

  float b1[2][4], b2[2][4]; int i1[2][4];
  #pragma unroll
  for (int mt=0;mt<2;++mt)
    #pragma unroll
    for (int r=0;r<4;++r){ b1[mt][r]=-3e38f; b2[mt][r]=-3e38f; i1[mt][r]=0; }

  for (int cb0 = 0; cb0 < K_; cb0 += 256) {
    __syncthreads();
    {
      const bf16x8* sh = (const bf16x8*)cbp_hi + cb0*4;
      const bf16x8* sl = (const bf16x8*)cbp_lo + cb0*4;
      #pragma unroll
      for (int v=0;v<4;++v){ ch[tid + v*256] = sh[tid + v*256];
                             cl[tid + v*256] = sl[tid + v*256]; }
      el[tid] = e2h[cb0 + tid];
    }
    __syncthreads();
    #pragma unroll
    for (int nt=0; nt<16; ++nt) {
      int cloc = nt*16 + colL;
      float ei = el[cloc];
      bf16x8 bh = ch[cloc*4 + g];
      bf16x8 bl = cl[cloc*4 + g];
      int nidx = cb0 + cloc;
      #pragma unroll
      for (int mt=0;mt<2;++mt) {
        f32x4 acc = {ei, ei, ei, ei};
        acc = mfma16(al[mt], bh, acc);
        acc = mfma16(ah[mt], bl, acc);
        acc = mfma16(ah[mt], bh, acc);
        #pragma unroll
        for (int r=0;r<4;++r) {
          float s = acc[r];
          b2[mt][r] = fmaxf(b2[mt][r], fminf(s, b1[mt][r]));
          if (s > b1[mt][r]) { b1[mt][r] = s; i1[mt][r] = nidx; }
        }
      }
    }
  }

  #pragma unroll
  for (int mask=1; mask<16; mask<<=1) {
    #pragma unroll
    for (int mt=0;mt<2;++mt)
      #pragma unroll
      for (int r=0;r<4;++r) {
        float o1 = __shfl_xor(b1[mt][r], mask);
        float o2 = __shfl_xor(b2[mt][r], mask);
        int   oi = __shfl_xor(i1[mt][r], mask);
        float nb2 = fmaxf(fminf(b1[mt][r], o1), fmaxf(b2[mt][r], o2));
        if (o1 > b1[mt][r]) { b1[mt][r] = o1; i1[mt][r] = oi; }
        b2[mt][r] = nb2;
      }
  }

  #pragma unroll
  for (int mt=0;mt<2;++mt)
    #pragma unroll
    for (int r=0;r<4;++r) {
      int m = m0 + mt*16 + g*4 + r;
      int idx = i1[mt][r];
      unsigned h0 = f2bf(cb[idx*C_ + 2*colL]);
      unsigned h1 = f2bf(cb[idx*C_ + 2*colL + 1]);
      ((unsigned*)q)[(((size_t)(colL>>2))*NPOS + m)*4 + (colL&3)] = h0 | (h1<<16);
      if (colL == 0 && (b1[mt][r] - b2[mt][r]) < 0.02f) {
        int slot = atomicAdd(cnt, 1);
        list[slot] = m;
      }
    }
}

// ---------------- exact f64 refine, LDS-staged codebook --------------------
__global__ __launch_bounds__(256) void refine_kernel(
    const int* __restrict__ cnt, const int* __restrict__ list,
    const float* __restrict__ z, const double* __restrict__ cb64,
    const double* __restrict__ e2, const float* __restrict__ cb,
    unsigned short* __restrict__ q) {
  __shared__ double lcb[64*33];             // 16.9KB
  __shared__ double le2[64];
  int tid = threadIdx.x, lane = tid&63, wv = tid>>6;
  int n_ref = cnt[0];
  int stride = (int)gridDim.x * 4;
  for (int base = 0; base < n_ref; base += stride) {
    int widx = base + (int)blockIdx.x*4 + wv;
    bool active = widx < n_ref;
    int m = active ? list[widx] : 0;
    double zr[C_];
    if (active) {
      int b = m >> 12, hw = m & 4095;
      const float* zp = z + (((size_t)b*C_) << 12) + hw;
      #pragma unroll
      for (int c=0;c<C_;++c) zr[c] = (double)zp[(size_t)c<<12];
    }
    double best = -1e300; int bi = 0;
    for (int ck = 0; ck < 16; ++ck) {
      __syncthreads();
      {
        const double* src = cb64 + (size_t)ck*2048 + (size_t)tid*8;
        int row = tid >> 2, col = (tid & 3)*8;
        #pragma unroll
        for (int j=0;j<8;++j) lcb[row*33 + col + j] = src[j];
        if (tid < 64) le2[tid] = e2[ck*64 + tid];
      }
      __syncthreads();
      if (active) {
        const double* e = &lcb[lane*33];
        double a0=0,a1=0,a2=0,a3=0;
        #pragma unroll
        for (int c=0;c<C_;c+=4) {
          a0 += zr[c  ]*e[c  ]; a1 += zr[c+1]*e[c+1];
          a2 += zr[c+2]*e[c+2]; a3 += zr[c+3]*e[c+3];
        }
        double s = 2.0*((a0+a1)+(a2+a3)) - le2[lane];
        if (s > best) { best = s; bi = ck*64 + lane; }
      }
    }
    #pragma unroll
    for (int mask=1; mask<64; mask<<=1) {
      double ob = __shfl_xor(best, mask);
      int    oi = __shfl_xor(bi, mask);
      if (ob > best || (ob == best && oi < bi)) { best = ob; bi = oi; }
    }
    if (active && lane < 16) {
      unsigned h0 = f2bf(cb[bi*C_ + 2*lane]);
      unsigned h1 = f2bf(cb[bi*C_ + 2*lane + 1]);
      ((unsigned*)q)[(((size_t)(lane>>2))*NPOS + m)*4 + (lane&3)] = h0 | (h1<<16);
    }
  }
}

// ---------------- convT1: 32->128, parity implicit GEMM --------------------
// in: q [cg4][n][8]; out: x1 [bl][cg16][128][128][8]
__global__ __launch_bounds__(256) void convt1_kernel(
    const unsigned short* __restrict__ q, const unsigned short* __restrict__ wt1p,
    const float* __restrict__ b1, const float* __restrict__ zpage,
    unsigned short* __restrict__ x1, int b0) {
  __shared__ unsigned short At[4*4*34*8];   // [k8][r][c][8] 8.5KB
  int tid = threadIdx.x;
  int p = tid>>6, py=(tid>>7)&1, px=(tid>>6)&1;
  int lane = tid&63, xi = lane&31, half = lane>>5, ocl = lane&31;
  int bl = blockIdx.z, b = b0 + bl;
  int Y0 = blockIdx.y*2, X0 = blockIdx.x*32;

  for (int s = tid; s < 544; s += 256) {
    int t = (s*1928)>>16;                   // s/34
    int c = s - t*34;
    int r = t & 3, k8 = t >> 2;
    int hg = Y0-1+r, wg = X0-1+c;
    const unsigned short* src =
        (hg>=0 && hg<64 && wg>=0 && wg<64)
            ? q + ((size_t)k8*NPOS + ((b<<12) + hg*64 + wg))*8
            : (const unsigned short*)zpage;
    *(bf16x8*)&At[s*8] = *(const bf16x8*)src;
  }
  __syncthreads();

  f32x16 acc[2][4];
  #pragma unroll
  for (int g=0;g<4;++g){
    float bv = b1[g*32+ocl];
    #pragma unroll
    for (int yr=0;yr<2;++yr){
      #pragma unroll
      for (int r=0;r<16;++r) acc[yr][g][r]=bv;
    }
  }

  #pragma unroll
  for (int c16=0;c16<2;++c16) {
    #pragma unroll
    for (int t=0;t<4;++t) {
      int j=t>>1, kx=t&1;
      int col = xi+px+kx;
      int rb = (c16*2+half)*4 + py + j;
      bf16x8 a0 = *(const bf16x8*)&At[((rb+0)*34+col)*8];
      bf16x8 a1 = *(const bf16x8*)&At[((rb+1)*34+col)*8];
      const unsigned short* wb = wt1p + ((size_t)(((p*2+c16)*4+t)*4)*64 + lane)*8;
      #pragma unroll
      for (int g=0;g<4;++g) {
        bf16x8 bf = *(const bf16x8*)(wb + g*512);
        acc[0][g] = mfma32(a0, bf, acc[0][g]);
        acc[1][g] = mfma32(a1, bf, acc[1][g]);
      }
    }
  }

  #pragma unroll
  for (int yr=0;yr<2;++yr) {
    int Y = 2*(Y0+yr)+py;
    #pragma unroll
    for (int g=0;g<4;++g) {
      int oc = g*32 + ocl, cg = oc>>3, o8 = oc&7;
      unsigned short* dst = x1 + ((((size_t)bl*16 + cg)*128 + Y)*128 + (2*X0+px))*8 + o8;
      #pragma unroll
      for (int r=0;r<16;++r) {
        int xo = (r&3) + 8*(r>>2) + 4*half;
        dst[(size_t)xo*16] = f2bf(fmaxf(acc[yr][g][r], 0.f));
      }
    }
  }
}

// ---------------- convT2: 128->64, 4-phase counted-vmcnt + setprio (T5) ----
// in: x1 [bl][cg16][128][128][8]; out: x2 [bl][cg8][256][256][8]
__global__ __launch_bounds__(512, 4) void convt2_kernel(
    const unsigned short* __restrict__ x1, const unsigned short* __restrict__ wt2p,
    const float* __restrict__ b2, const float* __restrict__ zpage,
    unsigned short* __restrict__ x2) {
  __shared__ unsigned short At[4*1024*8];   // 64KB: 4 phase regions
  int tid = threadIdx.x;
  int wv = __builtin_amdgcn_readfirstlane(tid>>6);
  int lane = tid&63;
  int p = wv>>1, yh = wv&1;
  int py = p>>1, px = p&1;
  int xi = lane&31, half = lane>>5, ocl = lane&31;
  int bl = blockIdx.z;
  int Y0 = blockIdx.y*4, X0 = blockIdx.x*32;

  auto issue = [&](int P) {
    int m = P>>1, h = P&1;
    const unsigned short* xsrc = x1 + ((size_t)bl*16 + m*8 + h*4)*128*128*8;
    #pragma unroll
    for (int it = 0; it < 2; ++it) {
      int u0 = it*512 + wv*64;              // wave-uniform
      int u = u0 + lane;
      int tl = (u*1928)>>16;                // u/34
      int c  = u - tl*34;
      int k8 = (tl*43)>>8;                  // tl/6
      int r  = tl - k8*6;
      int hg = Y0-1+r, wg = X0-1+c;
      bool v = (u < 816) && hg>=0 && hg<128 && wg>=0 && wg<128;
      const void* src = v ? (const void*)(xsrc + (((size_t)k8*128 + hg)*128 + wg)*8)
                          : (const void*)zpage;
      gload16(src, (void*)&At[((size_t)P*1024 + u0)*8]);
    }
  };

  f32x16 acc[2][2];
  #pragma unroll
  for (int g=0;g<2;++g){
    float bv = b2[g*32+ocl];
    #pragma unroll
    for (int yr=0;yr<2;++yr)
      #pragma unroll
      for (int r=0;r<16;++r) acc[yr][g][r]=bv;
  }

  auto compute = [&](int P) {
    int m = P>>1;
    const unsigned short* Ab = &At[(size_t)P*1024*8];
    __builtin_amdgcn_s_setprio(1);
    #pragma unroll
    for (int ci=0; ci<2; ++ci) {
      int c16 = (P&1)*2 + ci;
      #pragma unroll
      for (int t=0;t<4;++t) {
        int j=t>>1, kx=t&1;
        int col = xi+px+kx;
        int lrow = ((c16*2+half)&3)*6 + py + j + yh*2;
        bf16x8 a0 = *(const bf16x8*)&Ab[((lrow+0)*34+col)*8];
        bf16x8 a1 = *(const bf16x8*)&Ab[((lrow+1)*34+col)*8];
        const unsigned short* wb = wt2p + ((size_t)(((((p*2+m)*4+c16)*4+t)*2))*64 + lane)*8;
        bf16x8 bf0 = *(const bf16x8*)wb;
        bf16x8 bf1 = *(const bf16x8*)(wb + 512);
        acc[0][0]=mfma32(a0,bf0,acc[0][0]); acc[1][0]=mfma32(a1,bf0,acc[1][0]);
        acc[0][1]=mfma32(a0,bf1,acc[0][1]); acc[1][1]=mfma32(a1,bf1,acc[1][1]);
      }
    }
    __builtin_amdgcn_s_setprio(0);
  };

  issue(0); issue(1); issue(2);   // 6 outstanding per wave
  WAITVM(4); barrier_raw();       // phase 0 resident
  compute(0);
  issue(3);                       // 6 outstanding (ph1,2,3)
  WAITVM(4); barrier_raw();       // phase 1 resident
  compute(1);
  WAITVM(2); barrier_raw();       // phase 2 resident
  compute(2);
  WAITVM(0); barrier_raw();       // phase 3 resident
  compute(3);

  #pragma unroll
  for (int yr=0;yr<2;++yr) {
    int Y = 2*(Y0 + yh*2 + yr) + py;
    #pragma unroll
    for (int g=0;g<2;++g) {
      int oc = g*32 + ocl, cg = oc>>3, o8 = oc&7;
      unsigned short* dst = x2 + ((((size_t)bl*8 + cg)*256 + Y)*256 + (2*X0+px))*8 + o8;
      #pragma unroll
      for (int r=0;r<16;++r) {
        int xo = (r&3) + 8*(r>>2) + 4*half;
        dst[(size_t)xo*16] = f2bf(fmaxf(acc[yr][g][r], 0.f));
      }
    }
  }
}

// ---------------- conv3 3x3 64->3(+13 pad) + sigmoid, MFMA 16x16x32 --------
// in: x2 [bl][cg8][256][256][8]. y-tile 8, 512 threads (8 waves x 1 row),
// 42.2KB LDS -> 3 blocks/CU = 24 waves/CU; halo ratio 1.25.
__global__ __launch_bounds__(512) void conv3_kernel(
    const unsigned short* __restrict__ x2, const unsigned short* __restrict__ w3p,
    const float* __restrict__ b3, const float* __restrict__ zpage,
    float* __restrict__ out, int b0) {
  __shared__ unsigned short Xt[2640*8];     // 42.2KB [k8 4][row 10][col 66][8]
  int tid = threadIdx.x, w = tid>>6, lane = tid&63;
  int xi = lane&15, k8A = (lane>>4)&3, oc = lane&15;
  int bl = blockIdx.z, b = b0 + bl;
  int y0 = blockIdx.y*8, x0 = blockIdx.x*64;
  int y = y0 + w;

  f32x4 acc[4];
  float bv = (oc<3) ? b3[oc] : 0.f;
  #pragma unroll
  for (int mt=0;mt<4;++mt){ acc[mt][0]=bv; acc[mt][1]=bv; acc[mt][2]=bv; acc[mt][3]=bv; }

  for (int c=0;c<2;++c) {
    __syncthreads();
    for (int s = tid; s < 2640; s += 512) {
      int t = (s*993)>>16;                  // s/66 (exact for s<2640)
      int cc = s - t*66;
      int k8 = (t*26)>>8;                   // t/10 (t<40)
      int r = t - k8*10;
      int rf = y0-1+r, cf = x0-1+cc;
      const unsigned short* src =
          (rf>=0 && rf<256 && cf>=0 && cf<256)
              ? x2 + ((((size_t)bl*8 + c*4 + k8)*256 + rf)*256 + cf)*8
              : (const unsigned short*)zpage;
      *(bf16x8*)&Xt[s*8] = *(const bf16x8*)src;
    }
    __syncthreads();

    #pragma unroll
    for (int t=0;t<9;++t) {
      int dy = t/3, dx = t - 3*dy;
      bf16x8 bf = *(const bf16x8*)(w3p + ((size_t)(t*2+c)*64 + lane)*8);
      #pragma unroll
      for (int mt=0;mt<4;++mt) {
        bf16x8 a = *(const bf16x8*)&Xt[((size_t)(k8A*10 + (w+dy))*66 + (mt*16 + xi + dx))*8];
        acc[mt] = mfma16(a, bf, acc[mt]);
      }
    }
  }

  if (oc < 3) {
    #pragma unroll
    for (int mt=0;mt<4;++mt) {
      f32x4 v;
      #pragma unroll
      for (int r=0;r<4;++r) v[r] = 1.f/(1.f + __expf(-acc[mt][r]));
      int x = x0 + mt*16 + ((lane>>4)&3)*4;
      *(f32x4*)(out + (((size_t)b*3 + oc)*256 + y)*256 + x) = v;
    }
  }
}

// ---------------------------------------------------------------------------
extern "C" void kernel_launch(void* const* d_in, const int* in_sizes, int n_in,
                              void* d_out, int out_size, void* d_ws, size_t ws_size,
                              hipStream_t stream) {
  const float* z  = (const float*)d_in[0];
  const float* cb = (const float*)d_in[1];
  const float* w1 = (const float*)d_in[2];
  const float* b1 = (const float*)d_in[3];
  const float* w2 = (const float*)d_in[4];
  const float* b2 = (const float*)d_in[5];
  const float* w3 = (const float*)d_in[6];
  const float* b3 = (const float*)d_in[7];
  float* out = (float*)d_out;

  char* ws = (char*)d_ws;
  size_t off = 0;
  auto alloc = [&](size_t bytes) -> void* {
    void* p = (void*)(ws + off);
    off += (bytes + 255) & ~(size_t)255;
    return p;
  };
  double* cb64         = (double*)alloc((size_t)K_*C_*8);
  double* e2           = (double*)alloc((size_t)K_*8);
  float*  zpage        = (float*)alloc(256);
  unsigned short* cbph = (unsigned short*)alloc((size_t)K_*C_*2);
  unsigned short* cbpl = (unsigned short*)alloc((size_t)K_*C_*2);
  float*  e2h          = (float*)alloc((size_t)K_*4);
  int*    cnt          = (int*)alloc(256);
  int*    list         = (int*)alloc((size_t)NPOS*4);
  unsigned short* zth  = (unsigned short*)alloc((size_t)NPOS*C_*2);
  unsigned short* ztl  = (unsigned short*)alloc((size_t)NPOS*C_*2);
  unsigned short* wt1p = (unsigned short*)alloc((size_t)65536*2);
  unsigned short* wt2p = (unsigned short*)alloc((size_t)131072*2);
  unsigned short* w3p  = (unsigned short*)alloc((size_t)9216*2);
  unsigned short* q    = (unsigned short*)alloc((size_t)NPOS*C_*2);
  size_t fixed = off;

  // per-batch: x1 16*128*128*8 bf16 (4.19MB) + x2 8*256*256*8 bf16 (8.39MB)
  size_t per_b = ((size_t)16*128*128*8 + (size_t)8*256*256*8) * 2;
  long long avail = (long long)ws_size - (long long)fixed;
  int chunk = (avail >= (long long)per_b) ? (int)(avail / (long long)per_b) : 1;
  if (chunk > B_) chunk = B_;
  // clamp to a divisor of 32 (avoid a lopsided tail dispatch)
  if      (chunk >= 32) chunk = 32;
  else if (chunk >= 16) chunk = 16;
  else if (chunk >=  8) chunk =  8;
  else if (chunk >=  4) chunk =  4;
  else if (chunk >=  2) chunk =  2;
  else                  chunk =  1;
  unsigned short* x1 = (unsigned short*)alloc((size_t)chunk*16*128*128*8*2);
  unsigned short* x2 = (unsigned short*)alloc((size_t)chunk*8*256*256*8*2);

  prep_kernel<<<512, 256, 0, stream>>>(cb, w1, w2, w3, cb64, e2, cbph, cbpl,
                                       e2h, wt1p, wt2p, w3p, zpage, cnt);
  zprep_kernel<<<512, 256, 0, stream>>>(z, zth, ztl);
  quantm_kernel<<<1024, 256, 0, stream>>>(zth, ztl, cbph, cbpl, e2h, cb,
                                          q, cnt, list);
  refine_kernel<<<512, 256, 0, stream>>>(cnt, list, z, cb64, e2, cb, q);

  for (int b0 = 0; b0 < B_; b0 += chunk) {
    int nb = (B_ - b0 < chunk) ? (B_ - b0) : chunk;
    convt1_kernel<<<dim3(2,32,nb), 256, 0, stream>>>(q, wt1p, b1, zpage, x1, b0);
    convt2_kernel<<<dim3(4,32,nb), 512, 0, stream>>>(x1, wt2p, b2, zpage, x2);
    conv3_kernel <<<dim3(4,32,nb), 512, 0, stream>>>(x2, w3p, b3, zpage, out, b0);
  }
}